// Round 1
// baseline (580.648 us; speedup 1.0000x reference)
//
#include <hip/hip_runtime.h>

// GridSamplePScan: out[b,t,c] = sum_{k<=t} bilinear(images[b,k,c], wrap(base + cum_t - cum_k))
// B=4, L=32, C=16, H=W=64, fp32.

constexpr int BN = 4, LN = 32, CN = 16, HN = 64, WN = 64;
constexpr int HWn = HN * WN;                 // 4096
constexpr int FRAME = CN * HWn;              // 65536 floats per (b,l)
constexpr size_t TIMG_BYTES = (size_t)BN * LN * FRAME * 4;  // 32 MB

// ---------------------------------------------------------------------------
// Transpose images [B,L,C,H,W] -> [B,L,H,W,C] so one bilinear corner for all
// 16 channels is a single aligned 64B cell (4x float4 per lane, fully used).
// ---------------------------------------------------------------------------
__global__ __launch_bounds__(256) void transpose_chw_hwc(
        const float* __restrict__ img, float* __restrict__ timg) {
    const int bi   = blockIdx.x;      // frame*16 + tile
    const int tile = bi & 15;
    const int frame = bi >> 4;        // b*L + l
    const int p = (tile << 8) + threadIdx.x;   // pixel index h*W+w

    const float* src = img + (size_t)frame * FRAME + p;
    float v[16];
#pragma unroll
    for (int c = 0; c < 16; ++c) v[c] = src[c * HWn];   // coalesced reads

    float4* dst = reinterpret_cast<float4*>(timg + ((size_t)frame * HWn + p) * 16);
#pragma unroll
    for (int q = 0; q < 4; ++q)
        dst[q] = make_float4(v[4*q+0], v[4*q+1], v[4*q+2], v[4*q+3]);
}

// ---------------------------------------------------------------------------
// Main kernel. One thread = one output pixel of one (b,t). Loops k = 0..t.
// FAST: gather from channel-interleaved timg (4x dwordx4 per corner).
// !FAST: gather from original layout (4 scalar loads per channel) — fallback
//        when d_ws is too small for the transposed copy.
// ---------------------------------------------------------------------------
template<bool FAST>
__global__ __launch_bounds__(256) void gsps_kernel(
        const float* __restrict__ flows,
        const float* __restrict__ img,
        float* __restrict__ out) {
    const int bi   = blockIdx.x;
    const int tile = bi & 15;
    const int rest = bi >> 4;
    const int t = 31 - (rest & 31);   // heavy blocks (large t) first
    const int b = rest >> 5;
    const int p = (tile << 8) + threadIdx.x;
    const int h = p >> 6, w = p & 63;

    // base grid: (idx + 0.5) * (2/64) - 1
    const float base_x = ((float)w + 0.5f) * 0.03125f - 1.0f;
    const float base_y = ((float)h + 0.5f) * 0.03125f - 1.0f;

    // flows[b,k,comp,h,w] = fl[(2k+comp)*HW]
    const float* fl = flows + (size_t)b * (LN * 2 * HWn) + p;

    // cum_t = sequential ascending sum (matches jnp.cumsum ordering)
    float ctx = 0.f, cty = 0.f;
    for (int j = 0; j <= t; ++j) {
        ctx += fl[(2*j    ) * HWn];
        cty += fl[(2*j + 1) * HWn];
    }

    float acc[16];
#pragma unroll
    for (int c = 0; c < 16; ++c) acc[c] = 0.f;

    float ckx = 0.f, cky = 0.f;
    for (int k = 0; k <= t; ++k) {
        // cum_k built with the same ascending order -> rel bitwise matches ref
        ckx += fl[(2*k    ) * HWn];
        cky += fl[(2*k + 1) * HWn];
        const float relx = ctx - ckx;
        const float rely = cty - cky;

        // wrap: mod(x+1, 2) - 1  (fmod is exact; matches XLA trunc-rem+adjust)
        float vx = (base_x + relx) + 1.0f;
        float vy = (base_y + rely) + 1.0f;
        float mx = fmodf(vx, 2.0f); mx = (mx < 0.0f) ? mx + 2.0f : mx;
        float my = fmodf(vy, 2.0f); my = (my < 0.0f) ? my + 2.0f : my;
        const float gx = mx - 1.0f;
        const float gy = my - 1.0f;

        const float ix = ((gx + 1.0f) * 0.5f) * 64.0f - 0.5f;  // in [-0.5, 63.5)
        const float iy = ((gy + 1.0f) * 0.5f) * 64.0f - 0.5f;
        const float x0f = floorf(ix), y0f = floorf(iy);
        const int x0 = (int)x0f, y0 = (int)y0f;                // x0 in [-1,63]
        const float wx1 = ix - x0f, wy1 = iy - y0f;
        const float wx0 = 1.0f - wx1, wy0 = 1.0f - wy1;
        const int x1 = x0 + 1, y1 = y0 + 1;                    // x1 in [0,64]

        const float fx0 = (x0 >= 0) ? 1.0f : 0.0f;
        const float fx1 = (x1 <= 63) ? 1.0f : 0.0f;
        const float fy0 = (y0 >= 0) ? 1.0f : 0.0f;
        const float fy1 = (y1 <= 63) ? 1.0f : 0.0f;
        const int x0c = (x0 < 0) ? 0 : x0;
        const int x1c = (x1 > 63) ? 63 : x1;
        const int y0c = (y0 < 0) ? 0 : y0;
        const int y1c = (y1 > 63) ? 63 : y1;

        const float w00 = (wx0 * wy0) * (fx0 * fy0);
        const float w10 = (wx1 * wy0) * (fx1 * fy0);
        const float w01 = (wx0 * wy1) * (fx0 * fy1);
        const float w11 = (wx1 * wy1) * (fx1 * fy1);

        if (FAST) {
            // timg cell (y,x) = 16 floats = 4 float4, 64B aligned
            const float4* fr = reinterpret_cast<const float4*>(img)
                             + (size_t)(b * LN + k) * (HWn * 4);
            const float4* p00 = fr + ((y0c << 6) + x0c) * 4;
            const float4* p10 = fr + ((y0c << 6) + x1c) * 4;
            const float4* p01 = fr + ((y1c << 6) + x0c) * 4;
            const float4* p11 = fr + ((y1c << 6) + x1c) * 4;
#pragma unroll
            for (int q = 0; q < 4; ++q) {
                const float4 g00 = p00[q], g10 = p10[q], g01 = p01[q], g11 = p11[q];
                acc[4*q+0] += ((w00*g00.x + w10*g10.x) + w01*g01.x) + w11*g11.x;
                acc[4*q+1] += ((w00*g00.y + w10*g10.y) + w01*g01.y) + w11*g11.y;
                acc[4*q+2] += ((w00*g00.z + w10*g10.z) + w01*g01.z) + w11*g11.z;
                acc[4*q+3] += ((w00*g00.w + w10*g10.w) + w01*g01.w) + w11*g11.w;
            }
        } else {
            const float* fr = img + (size_t)(b * LN + k) * FRAME;
            const int i00 = (y0c << 6) + x0c, i10 = (y0c << 6) + x1c;
            const int i01 = (y1c << 6) + x0c, i11 = (y1c << 6) + x1c;
#pragma unroll
            for (int c = 0; c < 16; ++c) {
                const float* pl = fr + c * HWn;
                acc[c] += ((w00*pl[i00] + w10*pl[i10]) + w01*pl[i01]) + w11*pl[i11];
            }
        }
    }

    // out[b,t,c,h,w]
    float* op = out + (size_t)(b * LN + t) * CN * HWn + p;
#pragma unroll
    for (int c = 0; c < 16; ++c) op[c * HWn] = acc[c];
}

extern "C" void kernel_launch(void* const* d_in, const int* in_sizes, int n_in,
                              void* d_out, int out_size, void* d_ws, size_t ws_size,
                              hipStream_t stream) {
    const float* flows  = (const float*)d_in[0];   // [4,32,2,64,64] f32
    const float* images = (const float*)d_in[1];   // [4,32,16,64,64] f32
    float* out = (float*)d_out;                    // [4,32,16,64,64] f32

    const int nblk = BN * LN * (HWn / 256);        // 2048 blocks, 256 thr
    if (ws_size >= TIMG_BYTES) {
        float* timg = (float*)d_ws;
        transpose_chw_hwc<<<nblk, 256, 0, stream>>>(images, timg);
        gsps_kernel<true><<<nblk, 256, 0, stream>>>(flows, timg, out);
    } else {
        gsps_kernel<false><<<nblk, 256, 0, stream>>>(flows, images, out);
    }
}

// Round 2
// 127.235 us; speedup vs baseline: 4.5636x; 4.5636x over previous
//
#include <hip/hip_runtime.h>

// GridSamplePScan: out[b,t,c] = sum_{k<=t} bilinear(images[b,k,c], wrap(base + cum_t - cum_k))
// B=4, L=32, C=16, H=W=64, fp32 in/out.
//
// R2 structure:
//   prep_timg : images fp32 [B,L,C,H,W] -> fp16 [B,L,H,W,C] (32B cell per pixel)
//   prep_cum  : cumsum(flows) fp32 -> ws as [B,L,H,W,{x,y}] (float2 per pixel)
//   gsps_fast : uniform-work main kernel; block = (b, pair, tile), does
//               t = 31-pair then t = pair  (33 k-iterations total, every block)
//               XCD swizzle: b = (blockIdx&7)>>1  -> each b's 4MB frame set
//               stays in one XCD-pair's L2.

constexpr int BN = 4, LN = 32, CN = 16, HN = 64, WN = 64;
constexpr int HWn = HN * WN;                  // 4096
constexpr int FRAME = CN * HWn;               // 65536 floats per (b,l)
constexpr size_t TIMG_BYTES = (size_t)BN * LN * HWn * CN * 2;   // 16 MB fp16
constexpr size_t CUM_BYTES  = (size_t)BN * LN * HWn * 2 * 4;    // 4 MB f32

typedef _Float16 half16 __attribute__((ext_vector_type(16)));

// ---------------------------------------------------------------------------
__global__ __launch_bounds__(256) void prep_timg(
        const float* __restrict__ img, half16* __restrict__ timg) {
    const int bi = blockIdx.x;
    const int tile = bi & 15;
    const int frame = bi >> 4;                 // b*L + l
    const int p = (tile << 8) + threadIdx.x;
    const float* src = img + (size_t)frame * FRAME + p;
    half16 v;
#pragma unroll
    for (int c = 0; c < 16; ++c) v[c] = (_Float16)src[c * HWn];  // coalesced
    timg[(size_t)frame * HWn + p] = v;         // 32B/lane, coalesced
}

// ---------------------------------------------------------------------------
__global__ __launch_bounds__(256) void prep_cum(
        const float* __restrict__ flows, float2* __restrict__ cum) {
    const int b = blockIdx.x >> 4;
    const int p = ((blockIdx.x & 15) << 8) + threadIdx.x;
    const float* fl = flows + (size_t)b * (LN * 2 * HWn) + p;
    float cx = 0.f, cy = 0.f;
    for (int l = 0; l < LN; ++l) {             // ascending adds == jnp.cumsum
        cx += fl[(2 * l) * HWn];
        cy += fl[(2 * l + 1) * HWn];
        cum[(size_t)(b * LN + l) * HWn + p] = make_float2(cx, cy);
    }
}

// ---------------------------------------------------------------------------
__global__ __launch_bounds__(256) void gsps_fast(
        const float2* __restrict__ cum,
        const half16* __restrict__ timg,
        float* __restrict__ out) {
    const int bid = blockIdx.x;                // 1024 blocks
    const int x = bid & 7;                     // nominal XCD slot
    const int b = x >> 1;                      // batch pinned to 2 XCDs
    const int half = x & 1;
    const int seq = bid >> 3;                  // [0,128)
    const int tile = (half << 3) + (seq & 7);  // [0,16)
    const int pair = seq >> 3;                 // [0,16)
    const int p = (tile << 8) + threadIdx.x;
    const int h = p >> 6, w = p & 63;

    const float base_x = ((float)w + 0.5f) * 0.03125f - 1.0f;
    const float base_y = ((float)h + 0.5f) * 0.03125f - 1.0f;

    const float2* cb = cum + (size_t)b * (LN * HWn) + p;
    const half16* fb = timg + (size_t)b * (LN * HWn);

#pragma unroll 1
    for (int ph = 0; ph < 2; ++ph) {
        const int t = ph ? pair : 31 - pair;   // 33 iterations total/block
        const float2 ct = cb[t * HWn];

        float acc[16];
#pragma unroll
        for (int c = 0; c < 16; ++c) acc[c] = 0.f;

        for (int k = 0; k <= t; ++k) {
            const float2 ck = cb[k * HWn];     // no serial dep: pipelines
            // wrap: mod(v+1, 2) - 1 ; v - 2*floor(v/2) is exact and equals
            // the trunc-rem+adjust form (fmod) bitwise.
            float vx = (base_x + (ct.x - ck.x)) + 1.0f;
            float vy = (base_y + (ct.y - ck.y)) + 1.0f;
            float mx = vx - 2.0f * floorf(vx * 0.5f);
            float my = vy - 2.0f * floorf(vy * 0.5f);
            const float gx = mx - 1.0f;
            const float gy = my - 1.0f;
            // ((gx+1)*0.5*64)-0.5 : *0.5 and *64 are exact scalings
            const float ix = (gx + 1.0f) * 32.0f - 0.5f;   // [-0.5, 63.5)
            const float iy = (gy + 1.0f) * 32.0f - 0.5f;

            const float x0f = floorf(ix), y0f = floorf(iy);
            const int x0 = (int)x0f, y0 = (int)y0f;        // [-1, 63]
            const float wx1 = ix - x0f, wy1 = iy - y0f;
            const float wx0 = 1.0f - wx1, wy0 = 1.0f - wy1;
            const int x1 = x0 + 1, y1 = y0 + 1;            // [0, 64]

            const float fx0 = (x0 >= 0) ? 1.0f : 0.0f;
            const float fx1 = (x1 <= 63) ? 1.0f : 0.0f;
            const float fy0 = (y0 >= 0) ? 1.0f : 0.0f;
            const float fy1 = (y1 <= 63) ? 1.0f : 0.0f;
            const int x0c = (x0 < 0) ? 0 : x0;
            const int x1c = (x1 > 63) ? 63 : x1;
            const int y0c = (y0 < 0) ? 0 : y0;
            const int y1c = (y1 > 63) ? 63 : y1;

            const float w00 = (wx0 * wy0) * (fx0 * fy0);
            const float w10 = (wx1 * wy0) * (fx1 * fy0);
            const float w01 = (wx0 * wy1) * (fx0 * fy1);
            const float w11 = (wx1 * wy1) * (fx1 * fy1);

            const half16* fr = fb + (size_t)k * HWn;
            const half16 g00 = fr[(y0c << 6) + x0c];       // 32B = 2x dwordx4
            const half16 g10 = fr[(y0c << 6) + x1c];
            const half16 g01 = fr[(y1c << 6) + x0c];
            const half16 g11 = fr[(y1c << 6) + x1c];
#pragma unroll
            for (int c = 0; c < 16; ++c) {
                acc[c] += ((w00 * (float)g00[c] + w10 * (float)g10[c])
                           + w01 * (float)g01[c]) + w11 * (float)g11[c];
            }
        }

        float* op = out + (size_t)(b * LN + t) * FRAME + p;
#pragma unroll
        for (int c = 0; c < 16; ++c) op[c * HWn] = acc[c];
    }
}

// ---------------------------------------------------------------------------
// Fallback (ws too small): direct fp32 gather, cum computed inline.
// ---------------------------------------------------------------------------
__global__ __launch_bounds__(256) void gsps_slow(
        const float* __restrict__ flows,
        const float* __restrict__ img,
        float* __restrict__ out) {
    const int bi = blockIdx.x;
    const int tile = bi & 15;
    const int rest = bi >> 4;
    const int t = 31 - (rest & 31);
    const int b = rest >> 5;
    const int p = (tile << 8) + threadIdx.x;
    const int h = p >> 6, w = p & 63;
    const float base_x = ((float)w + 0.5f) * 0.03125f - 1.0f;
    const float base_y = ((float)h + 0.5f) * 0.03125f - 1.0f;
    const float* fl = flows + (size_t)b * (LN * 2 * HWn) + p;

    float ctx = 0.f, cty = 0.f;
    for (int j = 0; j <= t; ++j) { ctx += fl[(2*j)*HWn]; cty += fl[(2*j+1)*HWn]; }

    float acc[16];
#pragma unroll
    for (int c = 0; c < 16; ++c) acc[c] = 0.f;

    float ckx = 0.f, cky = 0.f;
    for (int k = 0; k <= t; ++k) {
        ckx += fl[(2*k)*HWn]; cky += fl[(2*k+1)*HWn];
        float vx = (base_x + (ctx - ckx)) + 1.0f;
        float vy = (base_y + (cty - cky)) + 1.0f;
        float mx = vx - 2.0f * floorf(vx * 0.5f);
        float my = vy - 2.0f * floorf(vy * 0.5f);
        const float gx = mx - 1.0f, gy = my - 1.0f;
        const float ix = (gx + 1.0f) * 32.0f - 0.5f;
        const float iy = (gy + 1.0f) * 32.0f - 0.5f;
        const float x0f = floorf(ix), y0f = floorf(iy);
        const int x0 = (int)x0f, y0 = (int)y0f;
        const float wx1 = ix - x0f, wy1 = iy - y0f;
        const float wx0 = 1.0f - wx1, wy0 = 1.0f - wy1;
        const int x1 = x0 + 1, y1 = y0 + 1;
        const float fx0 = (x0 >= 0) ? 1.0f : 0.0f;
        const float fx1 = (x1 <= 63) ? 1.0f : 0.0f;
        const float fy0 = (y0 >= 0) ? 1.0f : 0.0f;
        const float fy1 = (y1 <= 63) ? 1.0f : 0.0f;
        const int x0c = (x0 < 0) ? 0 : x0, x1c = (x1 > 63) ? 63 : x1;
        const int y0c = (y0 < 0) ? 0 : y0, y1c = (y1 > 63) ? 63 : y1;
        const float w00 = (wx0*wy0)*(fx0*fy0), w10 = (wx1*wy0)*(fx1*fy0);
        const float w01 = (wx0*wy1)*(fx0*fy1), w11 = (wx1*wy1)*(fx1*fy1);
        const float* fr = img + (size_t)(b * LN + k) * FRAME;
        const int i00 = (y0c<<6)+x0c, i10 = (y0c<<6)+x1c;
        const int i01 = (y1c<<6)+x0c, i11 = (y1c<<6)+x1c;
#pragma unroll
        for (int c = 0; c < 16; ++c) {
            const float* pl = fr + c * HWn;
            acc[c] += ((w00*pl[i00] + w10*pl[i10]) + w01*pl[i01]) + w11*pl[i11];
        }
    }
    float* op = out + (size_t)(b * LN + t) * FRAME + p;
#pragma unroll
    for (int c = 0; c < 16; ++c) op[c * HWn] = acc[c];
}

extern "C" void kernel_launch(void* const* d_in, const int* in_sizes, int n_in,
                              void* d_out, int out_size, void* d_ws, size_t ws_size,
                              hipStream_t stream) {
    const float* flows  = (const float*)d_in[0];   // [4,32,2,64,64] f32
    const float* images = (const float*)d_in[1];   // [4,32,16,64,64] f32
    float* out = (float*)d_out;                    // [4,32,16,64,64] f32

    if (ws_size >= TIMG_BYTES + CUM_BYTES) {
        half16* timg = (half16*)d_ws;
        float2* cum  = (float2*)((char*)d_ws + TIMG_BYTES);
        prep_timg<<<BN * LN * (HWn / 256), 256, 0, stream>>>(images, timg);
        prep_cum<<<BN * (HWn / 256), 256, 0, stream>>>(flows, cum);
        gsps_fast<<<BN * (LN / 2) * (HWn / 256), 256, 0, stream>>>(cum, timg, out);
    } else {
        gsps_slow<<<BN * LN * (HWn / 256), 256, 0, stream>>>(flows, images, out);
    }
}